// Round 3
// baseline (560.197 us; speedup 1.0000x reference)
//
#include <hip/hip_runtime.h>
#include <math.h>

// MoLoRARouter: logits = x[16384,4096] @ gate_w[64,4096]^T (fp32) -> softmax
// -> top-2 -> renorm.  fp32 emulated as split-2 fp16 MFMA:
//   v = h + l/2048,  h = fp16(v), l = fp16((v-h)*2048)   (~22-24 mantissa bits)
//   logit = hh + (hl+lh)/2048 + ll/2048^2  -> error ~1e-6, fp32-reorder class.
//
// V3 (latency fix, round 2 counters: MfmaUtil 5%, VALUBusy 5%, occ 22.7% ->
// pure exposed latency at 2 waves/SIMD + 16-line B gathers):
//  - wconv writes w split-fp16 in FRAGMENT-MAJOR order: one MFMA B-fragment
//    = one contiguous 1 KB wave load (lane*16B). No more 16-row gathers.
//  - K-split 4 (was 2): 4096 waves -> 4 waves/SIMD TLP. Partials merged via
//    one 15 KB LDS exchange + single __syncthreads; wave 0 does top-2.
//  - x A-fragments still direct global->VGPR, depth-2 prefetch, converted
//    in-register. No main-loop barriers.

typedef _Float16 half8 __attribute__((ext_vector_type(8)));
typedef float floatx4 __attribute__((ext_vector_type(4)));

constexpr int Hdim  = 4096;
constexpr int Edim  = 64;
constexpr int NTOK  = 16384;
constexpr int KQ    = 1024;          // K range per wave (K-split 4)
constexpr int NB    = KQ / 64;       // 16 bodies (64 floats each)
constexpr float SCL  = 2048.0f;
constexpr float ISCL = 1.0f / 2048.0f;

// ---- pre-kernel: gate_w fp32 -> split fp16, fragment-major ----
// Fragment (kc = k/32 in [0,128), nt in [0,4), lane in [0,64)):
//   value = w[nt*16 + (lane&15)][kc*32 + (lane>>4)*8 + j], j=0..7
//   stored at wf[((kc*4 + nt)*64 + lane)*8 + j]
__global__ __launch_bounds__(256)
void wconv_kernel(const float* __restrict__ gw,
                  _Float16* __restrict__ whf,
                  _Float16* __restrict__ wlf)
{
    const int n    = blockIdx.x * 256 + threadIdx.x;   // 0..32767
    const int lane = n & 63;
    const int frag = n >> 6;           // 0..511
    const int nt   = frag & 3;
    const int kc   = frag >> 2;        // 0..127
    const int e    = nt * 16 + (lane & 15);
    const int k0   = kc * 32 + (lane >> 4) * 8;

    const float* src = gw + (size_t)e * Hdim + k0;
    const float4 v0 = *(const float4*)src;
    const float4 v1 = *(const float4*)(src + 4);
    const float* p0 = (const float*)&v0;
    const float* p1 = (const float*)&v1;
    half8 h, l;
    #pragma unroll
    for (int c = 0; c < 4; ++c) {
        _Float16 hh = (_Float16)p0[c];
        h[c] = hh;
        l[c] = (_Float16)((p0[c] - (float)hh) * SCL);
        hh = (_Float16)p1[c];
        h[c + 4] = hh;
        l[c + 4] = (_Float16)((p1[c] - (float)hh) * SCL);
    }
    *(half8*)(whf + (size_t)n * 8) = h;
    *(half8*)(wlf + (size_t)n * 8) = l;
}

// ---- main kernel: 4 waves/block, each 16 tokens x 64 experts x K=1024 ----
__global__ __launch_bounds__(256, 4)
void router_kernel(const float* __restrict__ x,
                   const _Float16* __restrict__ whf,
                   const _Float16* __restrict__ wlf,
                   float* __restrict__ out)
{
    __shared__ alignas(16) float sp[3][64][20];   // K-quarter partials (waves 1..3)

    const int tid  = threadIdx.x;
    const int wv   = tid >> 6;          // K-quarter owned by this wave
    const int lane = tid & 63;
    const int ln15 = lane & 15;
    const int quad = lane >> 4;
    const int t0   = blockIdx.x * 16;
    const int koff = wv * KQ;

    // A: per-lane base (row = lane&15, k = (lane>>4)*8 — verified map)
    const float* xa = x + (size_t)(t0 + ln15) * Hdim + koff + quad * 8;
    // B: fragment-major bases; offset for (kcLocal, nt) = (kcLocal*4+nt)*512 halves
    const _Float16* whb = whf + (size_t)wv * 65536 + lane * 8;
    const _Float16* wlb = wlf + (size_t)wv * 65536 + lane * 8;

    floatx4 accm[4], accc[4], accl[4];
    #pragma unroll
    for (int nt = 0; nt < 4; ++nt) {
        accm[nt] = (floatx4)0.0f;
        accc[nt] = (floatx4)0.0f;
        accl[nt] = (floatx4)0.0f;
    }

    float4 A0[4], A1[4];               // x raw, depth-2 rotation
    half8 bAh[4], bAl[4];              // B for kk=0 (prefetched one body ahead)
    half8 bBh[4], bBl[4];              // B for kk=1

    // ---- prologue ----
    #pragma unroll
    for (int j = 0; j < 4; ++j) {
        A0[j] = *(const float4*)(xa + 0 * 64 + (j >> 1) * 32 + (j & 1) * 4);
        A1[j] = *(const float4*)(xa + 1 * 64 + (j >> 1) * 32 + (j & 1) * 4);
    }
    #pragma unroll
    for (int nt = 0; nt < 4; ++nt) {
        bAh[nt] = *(const half8*)(whb + (size_t)(0 * 4 + nt) * 512);
        bAl[nt] = *(const half8*)(wlb + (size_t)(0 * 4 + nt) * 512);
        bBh[nt] = *(const half8*)(whb + (size_t)(1 * 4 + nt) * 512);
        bBl[nt] = *(const half8*)(wlb + (size_t)(1 * 4 + nt) * 512);
    }

    auto cvt8 = [&](const float4& a, const float4& b, half8& h, half8& l) {
        const float* pa = (const float*)&a;
        const float* pb = (const float*)&b;
        #pragma unroll
        for (int c = 0; c < 4; ++c) {
            _Float16 hh = (_Float16)pa[c];
            h[c] = hh;
            l[c] = (_Float16)((pa[c] - (float)hh) * SCL);
            hh = (_Float16)pb[c];
            h[c + 4] = hh;
            l[c + 4] = (_Float16)((pb[c] - (float)hh) * SCL);
        }
    };

    auto body = [&](float4 (&Acur)[4], int kt) {
        const int ktn = (kt + 1 < NB) ? kt + 1 : 0;   // clamped B prefetch
        const int ka  = (kt + 2 < NB) ? kt + 2 : 0;   // clamped A prefetch
        half8 ah, al;

        // kk = 0: compute with bA
        cvt8(Acur[0], Acur[1], ah, al);
        #pragma unroll
        for (int nt = 0; nt < 4; ++nt) {
            accm[nt] = __builtin_amdgcn_mfma_f32_16x16x32_f16(ah, bAh[nt], accm[nt], 0, 0, 0);
            accc[nt] = __builtin_amdgcn_mfma_f32_16x16x32_f16(ah, bAl[nt], accc[nt], 0, 0, 0);
            accc[nt] = __builtin_amdgcn_mfma_f32_16x16x32_f16(al, bAh[nt], accc[nt], 0, 0, 0);
            accl[nt] = __builtin_amdgcn_mfma_f32_16x16x32_f16(al, bAl[nt], accl[nt], 0, 0, 0);
        }
        // refill bA for next body's kk0 (contiguous 1 KB loads)
        #pragma unroll
        for (int nt = 0; nt < 4; ++nt) {
            bAh[nt] = *(const half8*)(whb + (size_t)((2 * ktn) * 4 + nt) * 512);
            bAl[nt] = *(const half8*)(wlb + (size_t)((2 * ktn) * 4 + nt) * 512);
        }

        // kk = 1: compute with bB
        cvt8(Acur[2], Acur[3], ah, al);
        #pragma unroll
        for (int nt = 0; nt < 4; ++nt) {
            accm[nt] = __builtin_amdgcn_mfma_f32_16x16x32_f16(ah, bBh[nt], accm[nt], 0, 0, 0);
            accc[nt] = __builtin_amdgcn_mfma_f32_16x16x32_f16(ah, bBl[nt], accc[nt], 0, 0, 0);
            accc[nt] = __builtin_amdgcn_mfma_f32_16x16x32_f16(al, bBh[nt], accc[nt], 0, 0, 0);
            accl[nt] = __builtin_amdgcn_mfma_f32_16x16x32_f16(al, bBl[nt], accl[nt], 0, 0, 0);
        }
        // refill bB for next body's kk1
        #pragma unroll
        for (int nt = 0; nt < 4; ++nt) {
            bBh[nt] = *(const half8*)(whb + (size_t)((2 * ktn + 1) * 4 + nt) * 512);
            bBl[nt] = *(const half8*)(wlb + (size_t)((2 * ktn + 1) * 4 + nt) * 512);
        }

        // A depth-2 prefetch into the buffer just consumed (used at kt+2)
        #pragma unroll
        for (int j = 0; j < 4; ++j)
            Acur[j] = *(const float4*)(xa + ka * 64 + (j >> 1) * 32 + (j & 1) * 4);
    };

    for (int kt = 0; kt < NB; kt += 2) {
        body(A0, kt);
        body(A1, kt + 1);
    }

    // ---- combine split terms; merge K-quarters through LDS (single barrier) ----
    floatx4 v[4];
    #pragma unroll
    for (int nt = 0; nt < 4; ++nt)
        v[nt] = accm[nt] + accc[nt] * ISCL + accl[nt] * (ISCL * ISCL);

    if (wv) {
        #pragma unroll
        for (int nt = 0; nt < 4; ++nt)
            *(floatx4*)&sp[wv - 1][lane][4 * nt] = v[nt];
    }
    __syncthreads();

    if (wv == 0) {
        #pragma unroll
        for (int q = 0; q < 3; ++q)
            #pragma unroll
            for (int nt = 0; nt < 4; ++nt)
                v[nt] += *(const floatx4*)&sp[q][lane][4 * nt];

        // D layout: token = quad*4 + i, expert = nt*16 + ln15.
        #pragma unroll
        for (int i = 0; i < 4; ++i) {
            float m1 = -INFINITY, m2 = -INFINITY;
            int i1 = 0, i2 = 0;
            #pragma unroll
            for (int nt = 0; nt < 4; ++nt) {
                const float val = v[nt][i];
                const int e = nt * 16 + ln15;
                if (val > m1)      { m2 = m1; i2 = i1; m1 = val; i1 = e; }
                else if (val > m2) { m2 = val; i2 = e; }
            }
            #pragma unroll
            for (int mk = 1; mk <= 8; mk <<= 1) {
                const float om1 = __shfl_xor(m1, mk);
                const int   oi1 = __shfl_xor(i1, mk);
                const float om2 = __shfl_xor(m2, mk);
                const int   oi2 = __shfl_xor(i2, mk);
                const bool aw = (m1 > om1) || (m1 == om1 && i1 < oi1);
                const float w1v = aw ? m1 : om1;  const int w1i = aw ? i1 : oi1;
                const float ca  = aw ? m2 : om2;  const int cai = aw ? i2 : oi2;
                const float cb  = aw ? om1 : m1;  const int cbi = aw ? oi1 : i1;
                const bool sw = (ca > cb) || (ca == cb && cai < cbi);
                m1 = w1v; i1 = w1i;
                m2 = sw ? ca : cb;
                i2 = sw ? cai : cbi;
            }
            if (ln15 == 0) {
                const float r   = expf(m2 - m1);
                const float inv = 1.0f / (1.0f + r);
                const int t = t0 + quad * 4 + i;
                float* ow = out + 2 * (size_t)t;
                ow[0] = inv;
                ow[1] = r * inv;
                float* oi = out + 2 * (size_t)NTOK + 2 * (size_t)t;
                oi[0] = (float)i1;
                oi[1] = (float)i2;
            }
        }
    }
}

extern "C" void kernel_launch(void* const* d_in, const int* in_sizes, int n_in,
                              void* d_out, int out_size, void* d_ws, size_t ws_size,
                              hipStream_t stream) {
    const float* x  = (const float*)d_in[0];   // [4,4096,4096] fp32
    const float* gw = (const float*)d_in[1];   // [64,4096] fp32
    float* out = (float*)d_out;                // weights(32768) ++ indices(32768)
    _Float16* whf = (_Float16*)d_ws;           // fragment-major split-high (512 KB)
    _Float16* wlf = whf + (size_t)Edim * Hdim; // fragment-major split-low  (512 KB)

    hipLaunchKernelGGL(wconv_kernel, dim3(128), dim3(256), 0, stream, gw, whf, wlf);
    hipLaunchKernelGGL(router_kernel, dim3(NTOK / 16), dim3(256), 0, stream,
                       x, whf, wlf, out);
}

// Round 4
// 382.177 us; speedup vs baseline: 1.4658x; 1.4658x over previous
//
#include <hip/hip_runtime.h>
#include <math.h>

// MoLoRARouter: logits = x[16384,4096] @ gate_w[64,4096]^T (fp32) -> softmax
// -> top-2 -> renorm.  fp32 emulated as split-2 fp16 MFMA:
//   v = h + l/2048,  h = fp16(v), l = fp16((v-h)*2048)   (~22-24 mantissa bits)
//   logit = hh + (hl+lh)/2048 + ll/2048^2  -> error ~1e-6, fp32-reorder class.
//
// V4: V3's 312 MB WRITE_SIZE = scratch spills (VGPR capped 64 vs ~170 demand);
// register prefetch is also compiler-sunk (V2: 80 VGPRs = live ranges shrunk).
// Fix: structures the compiler can't undo:
//  - x staged HBM->LDS via __builtin_amdgcn_global_load_lds (async, no VGPRs,
//    cannot be sunk/spilled). Double-buffered 16x128-float tiles, 1 barrier/step,
//    stage issued before compute (m97 pattern).
//  - Per-wave slice: 16 tokens x 16 experts, full K. acc 12 + B 32 VGPRs -> ~80
//    total, no spill. Grid 1024 = 4 blocks/CU = 16 waves/CU.
//  - LDS XOR swizzle at 16B granules, pre-swizzled GLOBAL source (linear LDS
//    dest as global_load_lds requires): ds_read_b128 -> 2 lanes/bank (free).
//  - w fragment-major split-fp16 from L2 (wconv pre-kernel, unchanged).

typedef _Float16 half8 __attribute__((ext_vector_type(8)));
typedef float floatx4 __attribute__((ext_vector_type(4)));

constexpr int Hdim = 4096;
constexpr int Edim = 64;
constexpr int NTOK = 16384;
constexpr int BK   = 128;          // K floats per tile
constexpr int NKT  = Hdim / BK;    // 32 steps
constexpr float SCL  = 2048.0f;
constexpr float ISCL = 1.0f / 2048.0f;

#define GLD_LDS16(gp, lp)                                              \
    __builtin_amdgcn_global_load_lds(                                  \
        (const __attribute__((address_space(1))) void*)(gp),           \
        (__attribute__((address_space(3))) void*)(lp), 16, 0, 0)

// ---- pre-kernel: gate_w fp32 -> split fp16, fragment-major ----
// Fragment (kc = k/32 in [0,128), nt in [0,4), lane in [0,64)):
//   value = w[nt*16 + (lane&15)][kc*32 + (lane>>4)*8 + j], j=0..7
//   stored at wf[((kc*4 + nt)*64 + lane)*8 + j]
__global__ __launch_bounds__(256)
void wconv_kernel(const float* __restrict__ gw,
                  _Float16* __restrict__ whf,
                  _Float16* __restrict__ wlf)
{
    const int n    = blockIdx.x * 256 + threadIdx.x;   // 0..32767
    const int lane = n & 63;
    const int frag = n >> 6;           // 0..511
    const int nt   = frag & 3;
    const int kc   = frag >> 2;        // 0..127
    const int e    = nt * 16 + (lane & 15);
    const int k0   = kc * 32 + (lane >> 4) * 8;

    const float* src = gw + (size_t)e * Hdim + k0;
    const float4 v0 = *(const float4*)src;
    const float4 v1 = *(const float4*)(src + 4);
    const float* p0 = (const float*)&v0;
    const float* p1 = (const float*)&v1;
    half8 h, l;
    #pragma unroll
    for (int c = 0; c < 4; ++c) {
        _Float16 hh = (_Float16)p0[c];
        h[c] = hh;
        l[c] = (_Float16)((p0[c] - (float)hh) * SCL);
        hh = (_Float16)p1[c];
        h[c + 4] = hh;
        l[c + 4] = (_Float16)((p1[c] - (float)hh) * SCL);
    }
    *(half8*)(whf + (size_t)n * 8) = h;
    *(half8*)(wlf + (size_t)n * 8) = l;
}

// ---- main kernel: block = 16 tokens, 4 waves; wave w = experts [16w,16w+16) ----
__global__ __launch_bounds__(256, 4)
void router_kernel(const float* __restrict__ x,
                   const _Float16* __restrict__ whf,
                   const _Float16* __restrict__ wlf,
                   float* __restrict__ out)
{
    // x tile: [16 rows][32 granules of 16B], slot = g ^ (row&7). 8 KiB x 2.
    __shared__ alignas(16) float  sx[2][16 * BK];
    __shared__ alignas(16) float4 sc[4][16];   // per-wave top-2 candidates

    const int tid  = threadIdx.x;
    const int w    = tid >> 6;
    const int lane = tid & 63;
    const int ln15 = lane & 15;
    const int quad = lane >> 4;
    const int sw   = ln15 & 7;
    const int t0   = blockIdx.x * 16;

    // staging mapping: instr p in {0,1}: row = w*4 + p*2 + (lane>>5),
    // LDS slot = lane&31, source granule = slot ^ (row&7)  (pre-swizzled source)
    const int r0 = w * 4 + (lane >> 5);
    const int r1 = r0 + 2;
    const int g0 = (lane & 31) ^ (r0 & 7);
    const int g1 = (lane & 31) ^ (r1 & 7);
    const float* px0 = x + (size_t)(t0 + r0) * Hdim + g0 * 4;
    const float* px1 = x + (size_t)(t0 + r1) * Hdim + g1 * 4;

    // B: fragment-major, this wave's expert slice nt=w
    const _Float16* whw = whf + (size_t)w * 512 + lane * 8;
    const _Float16* wlw = wlf + (size_t)w * 512 + lane * 8;

    floatx4 accm = (floatx4)0.0f, accc = (floatx4)0.0f, accl = (floatx4)0.0f;

    auto cvt8 = [&](const float4& a, const float4& b, half8& h, half8& l) {
        const float* pa = (const float*)&a;
        const float* pb = (const float*)&b;
        #pragma unroll
        for (int c = 0; c < 4; ++c) {
            _Float16 hh = (_Float16)pa[c];
            h[c] = hh;
            l[c] = (_Float16)((pa[c] - (float)hh) * SCL);
            hh = (_Float16)pb[c];
            h[c + 4] = hh;
            l[c + 4] = (_Float16)((pb[c] - (float)hh) * SCL);
        }
    };

    // ---- prologue: stage tile 0 into buf 0 ----
    GLD_LDS16(px0, &sx[0][w * 512]);
    GLD_LDS16(px1, &sx[0][w * 512 + 256]);
    px0 += BK; px1 += BK;
    __syncthreads();

    for (int kt = 0; kt < NKT; ++kt) {
        const int cur = kt & 1;
        // stage next tile first: HBM latency hides under this step's compute
        if (kt + 1 < NKT) {
            GLD_LDS16(px0, &sx[cur ^ 1][w * 512]);
            GLD_LDS16(px1, &sx[cur ^ 1][w * 512 + 256]);
            px0 += BK; px1 += BK;
        }

        // B fragments for this step's 4 k-chunks (L2-resident, contiguous 1 KB)
        half8 bh[4], bl[4];
        #pragma unroll
        for (int c = 0; c < 4; ++c) {
            const size_t kc = (size_t)(kt * 4 + c) * 2048;
            bh[c] = *(const half8*)(whw + kc);
            bl[c] = *(const half8*)(wlw + kc);
        }

        #pragma unroll
        for (int c = 0; c < 4; ++c) {
            const int s0 = (c * 8 + quad * 2) ^ sw;
            const float4 f0 = *(const float4*)&sx[cur][ln15 * BK + s0 * 4];
            const float4 f1 = *(const float4*)&sx[cur][ln15 * BK + (s0 ^ 1) * 4];
            half8 ah, al;
            cvt8(f0, f1, ah, al);
            accm = __builtin_amdgcn_mfma_f32_16x16x32_f16(ah, bh[c], accm, 0, 0, 0);
            accc = __builtin_amdgcn_mfma_f32_16x16x32_f16(ah, bl[c], accc, 0, 0, 0);
            accc = __builtin_amdgcn_mfma_f32_16x16x32_f16(al, bh[c], accc, 0, 0, 0);
            accl = __builtin_amdgcn_mfma_f32_16x16x32_f16(al, bl[c], accl, 0, 0, 0);
        }
        __syncthreads();   // staged(next) complete + everyone done reading cur
    }

    // ---- epilogue: combine split terms; top-2 ----
    // D layout: token = quad*4 + i, expert = w*16 + ln15.
    const floatx4 vv = accm + accc * ISCL + accl * (ISCL * ISCL);

    #pragma unroll
    for (int i = 0; i < 4; ++i) {
        float m1 = vv[i], m2 = -INFINITY;
        int i1 = w * 16 + ln15, i2 = 0;
        #pragma unroll
        for (int mk = 1; mk <= 8; mk <<= 1) {   // 16-lane butterfly over slice
            const float om1 = __shfl_xor(m1, mk);
            const int   oi1 = __shfl_xor(i1, mk);
            const float om2 = __shfl_xor(m2, mk);
            const int   oi2 = __shfl_xor(i2, mk);
            const bool aw = (m1 > om1) || (m1 == om1 && i1 < oi1);
            const float w1v = aw ? m1 : om1;  const int w1i = aw ? i1 : oi1;
            const float ca  = aw ? m2 : om2;  const int cai = aw ? i2 : oi2;
            const float cb  = aw ? om1 : m1;  const int cbi = aw ? oi1 : i1;
            const bool sw2 = (ca > cb) || (ca == cb && cai < cbi);
            m1 = w1v; i1 = w1i;
            m2 = sw2 ? ca : cb;
            i2 = sw2 ? cai : cbi;
        }
        if (ln15 == 0)
            sc[w][quad * 4 + i] = float4{m1, m2, (float)i1, (float)i2};
    }
    __syncthreads();

    if (tid < 16) {   // wave 0: merge the 4 expert-slice candidates per token
        float4 c = sc[0][tid];
        float m1 = c.x, m2 = c.y, i1 = c.z, i2 = c.w;
        #pragma unroll
        for (int q = 1; q < 4; ++q) {
            c = sc[q][tid];
            const float om1 = c.x, om2 = c.y, oi1 = c.z, oi2 = c.w;
            const bool aw = (m1 > om1) || (m1 == om1 && i1 < oi1);
            const float w1v = aw ? m1 : om1;  const float w1i = aw ? i1 : oi1;
            const float ca  = aw ? m2 : om2;  const float cai = aw ? i2 : oi2;
            const float cb  = aw ? om1 : m1;  const float cbi = aw ? oi1 : i1;
            const bool sw2 = (ca > cb) || (ca == cb && cai < cbi);
            m1 = w1v; i1 = w1i;
            m2 = sw2 ? ca : cb;
            i2 = sw2 ? cai : cbi;
        }
        const float r   = expf(m2 - m1);
        const float inv = 1.0f / (1.0f + r);
        const int t = t0 + tid;
        float* ow = out + 2 * (size_t)t;
        ow[0] = inv;
        ow[1] = r * inv;
        float* oi = out + 2 * (size_t)NTOK + 2 * (size_t)t;
        oi[0] = i1;
        oi[1] = i2;
    }
}

extern "C" void kernel_launch(void* const* d_in, const int* in_sizes, int n_in,
                              void* d_out, int out_size, void* d_ws, size_t ws_size,
                              hipStream_t stream) {
    const float* x  = (const float*)d_in[0];   // [4,4096,4096] fp32
    const float* gw = (const float*)d_in[1];   // [64,4096] fp32
    float* out = (float*)d_out;                // weights(32768) ++ indices(32768)
    _Float16* whf = (_Float16*)d_ws;           // fragment-major split-high (512 KB)
    _Float16* wlf = whf + (size_t)Edim * Hdim; // fragment-major split-low  (512 KB)

    hipLaunchKernelGGL(wconv_kernel, dim3(128), dim3(256), 0, stream, gw, whf, wlf);
    hipLaunchKernelGGL(router_kernel, dim3(NTOK / 16), dim3(256), 0, stream,
                       x, whf, wlf, out);
}